// Round 1
// baseline (92.068 us; speedup 1.0000x reference)
//
#include <hip/hip_runtime.h>

#define NN 512
#define DD 256
#define MARGIN 1.0f

// One block per anchor. Computes distances to all 512 points, compacts
// valid positive/negative distance lists, accumulates triplet hinge sum,
// writes per-anchor partial sum (fp32) and exact valid-triplet count (int).
__global__ __launch_bounds__(256) void triplet_partial(
    const float* __restrict__ e, const int* __restrict__ labels,
    float* __restrict__ partial, int* __restrict__ pcount)
{
    const int a    = blockIdx.x;
    const int t    = threadIdx.x;
    const int lane = t & 63;
    const int wave = t >> 6;

    __shared__ __align__(16) float ea[DD];   // anchor embedding
    __shared__ int   slab[NN];               // labels
    __shared__ float plist[NN];              // d_ap + margin, compacted
    __shared__ float nlist[NN];              // d_an, compacted
    __shared__ int   segP[8], segN[8];
    __shared__ float red[4];

    // ---- stage anchor row + labels ----
    ea[t] = e[(size_t)a * DD + t];
    slab[t]       = labels[t];
    slab[t + 256] = labels[t + 256];
    __syncthreads();

    const int la = slab[a];

    // ---- distances: thread t owns columns j = t and j = t+256 ----
    float acc0 = 0.f, acc1 = 0.f;
    const float4* r0 = reinterpret_cast<const float4*>(e + (size_t)t * DD);
    const float4* r1 = reinterpret_cast<const float4*>(e + (size_t)(t + 256) * DD);
    #pragma unroll 4
    for (int k = 0; k < DD / 4; ++k) {
        float4 v0 = r0[k];
        float4 v1 = r1[k];
        float4 ev = *reinterpret_cast<const float4*>(&ea[k * 4]); // LDS broadcast
        float d;
        d = ev.x - v0.x; acc0 = fmaf(d, d, acc0);
        d = ev.y - v0.y; acc0 = fmaf(d, d, acc0);
        d = ev.z - v0.z; acc0 = fmaf(d, d, acc0);
        d = ev.w - v0.w; acc0 = fmaf(d, d, acc0);
        d = ev.x - v1.x; acc1 = fmaf(d, d, acc1);
        d = ev.y - v1.y; acc1 = fmaf(d, d, acc1);
        d = ev.z - v1.z; acc1 = fmaf(d, d, acc1);
        d = ev.w - v1.w; acc1 = fmaf(d, d, acc1);
    }
    const float d0 = sqrtf(acc0);
    const float d1 = sqrtf(acc1);

    // ---- validity predicates ----
    const int l0 = slab[t];
    const int l1 = slab[t + 256];
    const bool vp0 = (l0 == la) && (t != a);
    const bool vp1 = (l1 == la) && (t + 256 != a);
    const bool vn0 = (l0 != la);
    const bool vn1 = (l1 != la);

    const unsigned long long mp0 = __ballot(vp0);
    const unsigned long long mp1 = __ballot(vp1);
    const unsigned long long mn0 = __ballot(vn0);
    const unsigned long long mn1 = __ballot(vn1);

    if (lane == 0) {
        segP[wave]     = __popcll(mp0);
        segP[4 + wave] = __popcll(mp1);
        segN[wave]     = __popcll(mn0);
        segN[4 + wave] = __popcll(mn1);
    }
    __syncthreads();

    // exclusive prefix over 8 segments (pass0 = waves 0..3, pass1 = 4..7)
    int baseP0 = 0, baseP1 = 0, baseN0 = 0, baseN1 = 0, totP = 0, totN = 0;
    #pragma unroll
    for (int s = 0; s < 8; ++s) {
        const int vP = segP[s], vN = segN[s];
        totP += vP; totN += vN;
        if (s < wave)     { baseP0 += vP; baseN0 += vN; }
        if (s < 4 + wave) { baseP1 += vP; baseN1 += vN; }
    }

    // ---- scatter compacted lists ----
    const unsigned long long lower = (lane == 0) ? 0ull : ((~0ull) >> (64 - lane));
    if (vp0) plist[baseP0 + __popcll(mp0 & lower)] = d0 + MARGIN;
    if (vp1) plist[baseP1 + __popcll(mp1 & lower)] = d1 + MARGIN;
    if (vn0) nlist[baseN0 + __popcll(mn0 & lower)] = d0;
    if (vn1) nlist[baseN1 + __popcll(mn1 & lower)] = d1;
    __syncthreads();

    // ---- pair loop: waves stride positives, lanes stride negatives ----
    float sum = 0.f;
    for (int p = wave; p < totP; p += 4) {
        const float dpm = plist[p];              // LDS broadcast
        for (int n = lane; n < totN; n += 64) {  // stride-1, conflict-free
            const float v = dpm - nlist[n];
            sum += fmaxf(v, 0.f);
        }
    }

    // ---- reduce ----
    #pragma unroll
    for (int off = 32; off > 0; off >>= 1) sum += __shfl_down(sum, off);
    if (lane == 0) red[wave] = sum;
    __syncthreads();
    if (t == 0) {
        partial[a] = red[0] + red[1] + red[2] + red[3];
        pcount[a]  = totP * totN;
    }
}

__global__ __launch_bounds__(256) void reduce_final(
    const float* __restrict__ partial, const int* __restrict__ pcount,
    float* __restrict__ out)
{
    const int t = threadIdx.x;
    double s = 0.0;
    long long c = 0;
    for (int i = t; i < NN; i += 256) { s += (double)partial[i]; c += (long long)pcount[i]; }
    __shared__ double sd[256];
    __shared__ long long sc[256];
    sd[t] = s; sc[t] = c;
    __syncthreads();
    for (int off = 128; off > 0; off >>= 1) {
        if (t < off) { sd[t] += sd[t + off]; sc[t] += sc[t + off]; }
        __syncthreads();
    }
    if (t == 0) out[0] = (float)(sd[0] / (double)sc[0]);
}

extern "C" void kernel_launch(void* const* d_in, const int* in_sizes, int n_in,
                              void* d_out, int out_size, void* d_ws, size_t ws_size,
                              hipStream_t stream) {
    const float* e      = (const float*)d_in[0];
    const int*   labels = (const int*)d_in[1];
    float* out     = (float*)d_out;
    float* partial = (float*)d_ws;
    int*   pcount  = (int*)((char*)d_ws + NN * sizeof(float));

    triplet_partial<<<NN, 256, 0, stream>>>(e, labels, partial, pcount);
    reduce_final<<<1, 256, 0, stream>>>(partial, pcount, out);
}

// Round 2
// 91.078 us; speedup vs baseline: 1.0109x; 1.0109x over previous
//
#include <hip/hip_runtime.h>

#define NN 512
#define DD 256
#define MARGIN 1.0f

// ---------------- K1: distance matrix ----------------
// 256 blocks: blockIdx.x = g*2 + h. Group g owns anchors [4g, 4g+4);
// half h owns columns j in [h*256, h*256+256). Thread t owns j = h*256 + t.
// Each block reads 256 embedding rows exactly once (67 MB total vs 268 MB
// in the per-anchor version). Anchor columns live in LDS as eas[k][4] so a
// single broadcast b128 read serves 4 anchors per k.
__global__ __launch_bounds__(256) void dist_kernel(
    const float* __restrict__ e, float* __restrict__ dist,
    float* __restrict__ gsum, int* __restrict__ gcnt, int* __restrict__ gdone)
{
    const int g = blockIdx.x >> 1;
    const int h = blockIdx.x & 1;
    const int t = threadIdx.x;
    const int j = h * 256 + t;
    const int a0 = g * 4;

    // zero the global accumulators K2 will use (any single thread, once)
    if (blockIdx.x == 0 && t == 0) { *gsum = 0.f; *gcnt = 0; *gdone = 0; }

    __shared__ __align__(16) float eas[DD][4];   // [k][anchor] interleaved

    #pragma unroll
    for (int ai = 0; ai < 4; ++ai)
        eas[t][ai] = e[(size_t)(a0 + ai) * DD + t];   // coalesced row reads
    __syncthreads();

    float acc0 = 0.f, acc1 = 0.f, acc2 = 0.f, acc3 = 0.f;
    const float4* rowj = reinterpret_cast<const float4*>(e + (size_t)j * DD);

    #pragma unroll 4
    for (int kb = 0; kb < DD / 4; ++kb) {
        const float4 v = rowj[kb];
        const float vv[4] = {v.x, v.y, v.z, v.w};
        #pragma unroll
        for (int q = 0; q < 4; ++q) {
            const float4 av = *reinterpret_cast<const float4*>(&eas[kb * 4 + q][0]); // LDS broadcast
            float d;
            d = av.x - vv[q]; acc0 = fmaf(d, d, acc0);
            d = av.y - vv[q]; acc1 = fmaf(d, d, acc1);
            d = av.z - vv[q]; acc2 = fmaf(d, d, acc2);
            d = av.w - vv[q]; acc3 = fmaf(d, d, acc3);
        }
    }

    // direct squared-diff is always >= 0; sqrt(0)=0 exactly on the diagonal
    dist[(size_t)(a0 + 0) * NN + j] = sqrtf(acc0);
    dist[(size_t)(a0 + 1) * NN + j] = sqrtf(acc1);
    dist[(size_t)(a0 + 2) * NN + j] = sqrtf(acc2);
    dist[(size_t)(a0 + 3) * NN + j] = sqrtf(acc3);
}

// ---------------- K2: per-anchor triplet accumulation ----------------
// One block per anchor. Reads its distance row coalesced, compacts valid
// positive/negative lists via ballot-scan, runs the pair loop, block-reduces,
// atomically accumulates, and the last-finished block writes sum/count.
__global__ __launch_bounds__(256) void pairs_kernel(
    const float* __restrict__ dist, const int* __restrict__ labels,
    float* __restrict__ gsum, int* __restrict__ gcnt, int* __restrict__ gdone,
    float* __restrict__ out)
{
    const int a    = blockIdx.x;
    const int t    = threadIdx.x;
    const int lane = t & 63;
    const int wave = t >> 6;

    __shared__ int   slab[NN];
    __shared__ float plist[NN];
    __shared__ float nlist[NN];
    __shared__ int   segP[8], segN[8];
    __shared__ float red[4];

    slab[t]       = labels[t];
    slab[t + 256] = labels[t + 256];
    __syncthreads();

    const int la = slab[a];
    const float d0 = dist[(size_t)a * NN + t];        // coalesced
    const float d1 = dist[(size_t)a * NN + t + 256];

    const int l0 = slab[t];
    const int l1 = slab[t + 256];
    const bool vp0 = (l0 == la) && (t != a);
    const bool vp1 = (l1 == la) && (t + 256 != a);
    const bool vn0 = (l0 != la);
    const bool vn1 = (l1 != la);

    const unsigned long long mp0 = __ballot(vp0);
    const unsigned long long mp1 = __ballot(vp1);
    const unsigned long long mn0 = __ballot(vn0);
    const unsigned long long mn1 = __ballot(vn1);

    if (lane == 0) {
        segP[wave]     = __popcll(mp0);
        segP[4 + wave] = __popcll(mp1);
        segN[wave]     = __popcll(mn0);
        segN[4 + wave] = __popcll(mn1);
    }
    __syncthreads();

    int baseP0 = 0, baseP1 = 0, baseN0 = 0, baseN1 = 0, totP = 0, totN = 0;
    #pragma unroll
    for (int s = 0; s < 8; ++s) {
        const int vP = segP[s], vN = segN[s];
        totP += vP; totN += vN;
        if (s < wave)     { baseP0 += vP; baseN0 += vN; }
        if (s < 4 + wave) { baseP1 += vP; baseN1 += vN; }
    }

    const unsigned long long lower = (lane == 0) ? 0ull : ((~0ull) >> (64 - lane));
    if (vp0) plist[baseP0 + __popcll(mp0 & lower)] = d0 + MARGIN;
    if (vp1) plist[baseP1 + __popcll(mp1 & lower)] = d1 + MARGIN;
    if (vn0) nlist[baseN0 + __popcll(mn0 & lower)] = d0;
    if (vn1) nlist[baseN1 + __popcll(mn1 & lower)] = d1;
    __syncthreads();

    float sum = 0.f;
    for (int p = wave; p < totP; p += 4) {
        const float dpm = plist[p];                  // LDS broadcast
        for (int n = lane; n < totN; n += 64) {      // stride-1, conflict-free
            const float v = dpm - nlist[n];
            sum += fmaxf(v, 0.f);
        }
    }

    #pragma unroll
    for (int off = 32; off > 0; off >>= 1) sum += __shfl_down(sum, off);
    if (lane == 0) red[wave] = sum;
    __syncthreads();

    if (t == 0) {
        atomicAdd(gsum, red[0] + red[1] + red[2] + red[3]);
        atomicAdd(gcnt, totP * totN);
        __threadfence();
        const int ticket = atomicAdd(gdone, 1);
        if (ticket == NN - 1) {
            const float s = atomicAdd(gsum, 0.0f);   // coherent read-back
            const int   c = atomicAdd(gcnt, 0);
            out[0] = s / (float)c;
        }
    }
}

extern "C" void kernel_launch(void* const* d_in, const int* in_sizes, int n_in,
                              void* d_out, int out_size, void* d_ws, size_t ws_size,
                              hipStream_t stream) {
    const float* e      = (const float*)d_in[0];
    const int*   labels = (const int*)d_in[1];
    float* out   = (float*)d_out;

    float* gsum  = (float*)d_ws;
    int*   gcnt  = (int*)d_ws + 1;
    int*   gdone = (int*)d_ws + 2;
    float* dist  = (float*)((char*)d_ws + 256);   // 1 MB distance matrix

    dist_kernel<<<256, 256, 0, stream>>>(e, dist, gsum, gcnt, gdone);
    pairs_kernel<<<NN, 256, 0, stream>>>(dist, labels, gsum, gcnt, gdone, out);
}

// Round 4
// 85.790 us; speedup vs baseline: 1.0732x; 1.0616x over previous
//
#include <hip/hip_runtime.h>

#define NN 512
#define DD 256
#define MARGIN 1.0f

// ---------------- K1: distance matrix ----------------
// 256 blocks: blockIdx.x = g*2 + h. Group g owns anchors [4g, 4g+4);
// half h owns columns j in [h*256, h*256+256). Thread t owns j = h*256 + t.
// Each block reads 256 embedding rows once (67 MB total L2 traffic).
__global__ __launch_bounds__(256) void dist_kernel(
    const float* __restrict__ e, float* __restrict__ dist,
    float* __restrict__ gsum, int* __restrict__ gcnt, int* __restrict__ gdone)
{
    const int g = blockIdx.x >> 1;
    const int h = blockIdx.x & 1;
    const int t = threadIdx.x;
    const int j = h * 256 + t;
    const int a0 = g * 4;

    if (blockIdx.x == 0 && t == 0) { *gsum = 0.f; *gcnt = 0; *gdone = 0; }

    __shared__ __align__(16) float eas[DD][4];   // [k][anchor] interleaved

    #pragma unroll
    for (int ai = 0; ai < 4; ++ai)
        eas[t][ai] = e[(size_t)(a0 + ai) * DD + t];   // coalesced row reads
    __syncthreads();

    float acc0 = 0.f, acc1 = 0.f, acc2 = 0.f, acc3 = 0.f;
    const float4* rowj = reinterpret_cast<const float4*>(e + (size_t)j * DD);

    #pragma unroll 4
    for (int kb = 0; kb < DD / 4; ++kb) {
        const float4 v = rowj[kb];
        const float vv[4] = {v.x, v.y, v.z, v.w};
        #pragma unroll
        for (int q = 0; q < 4; ++q) {
            const float4 av = *reinterpret_cast<const float4*>(&eas[kb * 4 + q][0]); // LDS broadcast
            float d;
            d = av.x - vv[q]; acc0 = fmaf(d, d, acc0);
            d = av.y - vv[q]; acc1 = fmaf(d, d, acc1);
            d = av.z - vv[q]; acc2 = fmaf(d, d, acc2);
            d = av.w - vv[q]; acc3 = fmaf(d, d, acc3);
        }
    }

    dist[(size_t)(a0 + 0) * NN + j] = sqrtf(acc0);
    dist[(size_t)(a0 + 1) * NN + j] = sqrtf(acc1);
    dist[(size_t)(a0 + 2) * NN + j] = sqrtf(acc2);
    dist[(size_t)(a0 + 3) * NN + j] = sqrtf(acc3);
}

// ---------------- K2: triplet accumulation, 2 anchors per block ----------------
// 256 blocks (one scheduling round). Labels read straight from L2 (no LDS
// stage, no barrier). Ballot-compaction per anchor into 4 LDS lists, two
// pair loops, block reduce, global atomics + last-block-done final divide.
__global__ __launch_bounds__(256) void pairs_kernel(
    const float* __restrict__ dist, const int* __restrict__ labels,
    float* __restrict__ gsum, int* __restrict__ gcnt, int* __restrict__ gdone,
    float* __restrict__ out)
{
    const int b    = blockIdx.x;
    const int a0   = b * 2;
    const int a1   = b * 2 + 1;
    const int t    = threadIdx.x;
    const int lane = t & 63;
    const int wave = t >> 6;

    __shared__ float pl0[NN], nl0[NN], pl1[NN], nl1[NN];
    __shared__ int   seg[4][8];          // [P0,N0,P1,N1][segment]
    __shared__ float red[4];

    const int l0  = labels[t];           // L2-resident broadcastish reads
    const int l1  = labels[t + 256];
    const int la0 = labels[a0];
    const int la1 = labels[a1];

    const float d00 = dist[(size_t)a0 * NN + t];
    const float d01 = dist[(size_t)a0 * NN + t + 256];
    const float d10 = dist[(size_t)a1 * NN + t];
    const float d11 = dist[(size_t)a1 * NN + t + 256];

    const bool vp00 = (l0 == la0) && (t != a0);
    const bool vp01 = (l1 == la0) && (t + 256 != a0);
    const bool vn00 = (l0 != la0);
    const bool vn01 = (l1 != la0);
    const bool vp10 = (l0 == la1) && (t != a1);
    const bool vp11 = (l1 == la1) && (t + 256 != a1);
    const bool vn10 = (l0 != la1);
    const bool vn11 = (l1 != la1);

    const unsigned long long mp00 = __ballot(vp00), mp01 = __ballot(vp01);
    const unsigned long long mn00 = __ballot(vn00), mn01 = __ballot(vn01);
    const unsigned long long mp10 = __ballot(vp10), mp11 = __ballot(vp11);
    const unsigned long long mn10 = __ballot(vn10), mn11 = __ballot(vn11);

    if (lane == 0) {
        seg[0][wave] = __popcll(mp00); seg[0][4 + wave] = __popcll(mp01);
        seg[1][wave] = __popcll(mn00); seg[1][4 + wave] = __popcll(mn01);
        seg[2][wave] = __popcll(mp10); seg[2][4 + wave] = __popcll(mp11);
        seg[3][wave] = __popcll(mn10); seg[3][4 + wave] = __popcll(mn11);
    }
    __syncthreads();

    // exclusive prefix per list; all indices compile-time so arrays stay in regs
    int base0[4], base1[4], tot[4];
    #pragma unroll
    for (int li = 0; li < 4; ++li) {
        int b0 = 0, b1 = 0, tt = 0;
        #pragma unroll
        for (int s = 0; s < 8; ++s) {
            const int v = seg[li][s];
            tt += v;
            if (s < wave)     b0 += v;
            if (s < 4 + wave) b1 += v;
        }
        base0[li] = b0; base1[li] = b1; tot[li] = tt;
    }

    const unsigned long long lower = (lane == 0) ? 0ull : ((~0ull) >> (64 - lane));
    if (vp00) pl0[base0[0] + __popcll(mp00 & lower)] = d00 + MARGIN;
    if (vp01) pl0[base1[0] + __popcll(mp01 & lower)] = d01 + MARGIN;
    if (vn00) nl0[base0[1] + __popcll(mn00 & lower)] = d00;
    if (vn01) nl0[base1[1] + __popcll(mn01 & lower)] = d01;
    if (vp10) pl1[base0[2] + __popcll(mp10 & lower)] = d10 + MARGIN;
    if (vp11) pl1[base1[2] + __popcll(mp11 & lower)] = d11 + MARGIN;
    if (vn10) nl1[base0[3] + __popcll(mn10 & lower)] = d10;
    if (vn11) nl1[base1[3] + __popcll(mn11 & lower)] = d11;
    __syncthreads();

    float sum = 0.f;
    for (int p = wave; p < tot[0]; p += 4) {
        const float dpm = pl0[p];                    // LDS broadcast
        for (int n = lane; n < tot[1]; n += 64)      // stride-1, conflict-free
            sum += fmaxf(dpm - nl0[n], 0.f);
    }
    for (int p = wave; p < tot[2]; p += 4) {
        const float dpm = pl1[p];
        for (int n = lane; n < tot[3]; n += 64)
            sum += fmaxf(dpm - nl1[n], 0.f);
    }

    #pragma unroll
    for (int off = 32; off > 0; off >>= 1) sum += __shfl_down(sum, off);
    if (lane == 0) red[wave] = sum;
    __syncthreads();

    if (t == 0) {
        atomicAdd(gsum, red[0] + red[1] + red[2] + red[3]);
        atomicAdd(gcnt, tot[0] * tot[1] + tot[2] * tot[3]);
        __threadfence();
        const int ticket = atomicAdd(gdone, 1);
        if (ticket == 255) {
            const float s = atomicAdd(gsum, 0.0f);   // coherent read-back
            const int   c = atomicAdd(gcnt, 0);
            out[0] = s / (float)c;
        }
    }
}

extern "C" void kernel_launch(void* const* d_in, const int* in_sizes, int n_in,
                              void* d_out, int out_size, void* d_ws, size_t ws_size,
                              hipStream_t stream) {
    const float* e      = (const float*)d_in[0];
    const int*   labels = (const int*)d_in[1];
    float* out   = (float*)d_out;

    float* gsum  = (float*)d_ws;
    int*   gcnt  = (int*)d_ws + 1;
    int*   gdone = (int*)d_ws + 2;
    float* dist  = (float*)((char*)d_ws + 256);   // 1 MB distance matrix

    dist_kernel<<<256, 256, 0, stream>>>(e, dist, gsum, gcnt, gdone);
    pairs_kernel<<<256, 256, 0, stream>>>(dist, labels, gsum, gcnt, gdone, out);
}